// Round 1
// baseline (222.078 us; speedup 1.0000x reference)
//
#include <hip/hip_runtime.h>

// Net_19387482374339: fused 3-step LSTM (HID=IN=1) + linear head over groups of 6 seqs.
// One thread per output element (group of 6 sequences, 18 x-values, 18 LSTM steps).
//
// Math restructuring (trans-op minimization):
//   sigmoid(z) = 1/(1+exp2(-L*z)),  tanh(z) = (E-1)/(E+1) with E = exp2(2L*z), L = log2(e)
//   Gate weights pre-scaled by -L (i,f,o) / +2L (g) so gate arg feeds v_exp_f32 directly.
//   c_new = f*c + i*tanh(g) merged over one rcp:
//     = [c*(1+Ei)(1+Eg) + (Eg-1)*(1+Ef)] * rcp((1+Ei)(1+Eg)(1+Ef))
//   h = o*tanh(c) merged over one rcp:
//     = (Ec-1) * rcp((1+Eo)(Ec+1))
//   => 7 trans/timestep (5 exp2 + 2 rcp), 6 at t=0 (f-gate dead, c0=0).

constexpr float L2E = 1.4426950408889634f;

#if __has_builtin(__builtin_amdgcn_exp2f)
#define EXP2(x) __builtin_amdgcn_exp2f(x)
#else
#define EXP2(x) exp2f(x)
#endif
#if __has_builtin(__builtin_amdgcn_rcpf)
#define RCP(x) __builtin_amdgcn_rcpf(x)
#else
#define RCP(x) (1.0f / (x))
#endif

__global__ __launch_bounds__(256) void lstm_head_kernel(
    const float* __restrict__ x,
    const float* __restrict__ w_ih, const float* __restrict__ w_hh,
    const float* __restrict__ b_ih, const float* __restrict__ b_hh,
    const float* __restrict__ w_lin, const float* __restrict__ b_lin,
    float* __restrict__ out, int n_groups)
{
    const int g = blockIdx.x * 256 + threadIdx.x;

    // ---- uniform params (uniform addresses -> scalar loads); pre-scaled ----
    float Ax[4], Ah[4], Ab[4];
#pragma unroll
    for (int k = 0; k < 4; ++k) {
        const float sc = (k == 2) ? (2.0f * L2E) : (-L2E);
        Ax[k] = sc * w_ih[k];
        Ah[k] = sc * w_hh[k];
        Ab[k] = sc * (b_ih[k] + b_hh[k]);
    }
    float wl[18];
#pragma unroll
    for (int k = 0; k < 18; ++k) wl[k] = w_lin[k];
    const float bl = b_lin[0];

    if (g >= n_groups) return;

    // ---- 18 contiguous x values, float2-vectorized (8B-aligned: 72B/thread) ----
    const float2* xp = reinterpret_cast<const float2*>(x) + (size_t)g * 9;
    float xs[18];
#pragma unroll
    for (int k = 0; k < 9; ++k) {
        float2 v = xp[k];
        xs[2 * k]     = v.x;
        xs[2 * k + 1] = v.y;
    }

    float acc = bl;
#pragma unroll
    for (int j = 0; j < 6; ++j) {
        // ---- t = 0: h=0, c=0 (f-gate irrelevant) ----
        const float x0 = xs[3 * j];
        float ai = fmaf(x0, Ax[0], Ab[0]);
        float ag = fmaf(x0, Ax[2], Ab[2]);
        float ao = fmaf(x0, Ax[3], Ab[3]);
        float Ei = EXP2(ai), Eg = EXP2(ag), Eo = EXP2(ao);
        float t1 = Ei + 1.0f, t2 = Eg + 1.0f;
        float c = (t2 - 2.0f) * RCP(t1 * t2);          // i * tanh(g)
        float Ec = EXP2(2.0f * L2E * c);
        float t5 = Ec + 1.0f;
        float h = (t5 - 2.0f) * RCP((Eo + 1.0f) * t5); // o * tanh(c)
        acc = fmaf(h, wl[3 * j], acc);

        // ---- t = 1, 2 ----
#pragma unroll
        for (int t = 1; t < 3; ++t) {
            const float xv = xs[3 * j + t];
            float bi = fmaf(xv, Ax[0], Ab[0]);
            float bf = fmaf(xv, Ax[1], Ab[1]);
            float bg = fmaf(xv, Ax[2], Ab[2]);
            float bo = fmaf(xv, Ax[3], Ab[3]);
            float ai2 = fmaf(h, Ah[0], bi);
            float af2 = fmaf(h, Ah[1], bf);
            float ag2 = fmaf(h, Ah[2], bg);
            float ao2 = fmaf(h, Ah[3], bo);
            float Ei2 = EXP2(ai2), Ef2 = EXP2(af2), Eg2 = EXP2(ag2), Eo2 = EXP2(ao2);
            float u1 = Ei2 + 1.0f, u2 = Eg2 + 1.0f, u3 = Ef2 + 1.0f;
            float IG = u1 * u2;
            float R  = RCP(IG * u3);
            float num = fmaf(c, IG, (u2 - 2.0f) * u3);
            c = num * R;                                // f*c + i*tanh(g)
            float Ec2 = EXP2(2.0f * L2E * c);
            float v5 = Ec2 + 1.0f;
            h = (v5 - 2.0f) * RCP((Eo2 + 1.0f) * v5);  // o * tanh(c)
            acc = fmaf(h, wl[3 * j + t], acc);
        }
    }
    out[g] = acc;
}

extern "C" void kernel_launch(void* const* d_in, const int* in_sizes, int n_in,
                              void* d_out, int out_size, void* d_ws, size_t ws_size,
                              hipStream_t stream) {
    const float* x     = (const float*)d_in[0];
    const float* w_ih  = (const float*)d_in[1];
    const float* w_hh  = (const float*)d_in[2];
    const float* b_ih  = (const float*)d_in[3];
    const float* b_hh  = (const float*)d_in[4];
    const float* w_lin = (const float*)d_in[5];
    const float* b_lin = (const float*)d_in[6];
    float* out = (float*)d_out;

    const int n_groups = in_sizes[0] / 18;  // B*SEQ*IN / 18 = B/6
    const int grid = (n_groups + 255) / 256;
    lstm_head_kernel<<<grid, 256, 0, stream>>>(
        x, w_ih, w_hh, b_ih, b_hh, w_lin, b_lin, out, n_groups);
}